// Round 3
// baseline (23183.694 us; speedup 1.0000x reference)
//
#include <hip/hip_runtime.h>

// ---------------------------------------------------------------------------
// SimpleLSTM: 2-layer LSTM (B=32,T=512,D=512,H=1024) + output proj (O=512).
// Strategy:
//   conv kernels : fp32 -> f16, weights rearranged into MFMA B-frag order
//   zx0_gemm     : Zx0[t][wg][m][c] = x@Wx0 + b0  (parallel over all T)
//   lstm_persist : 256 persistent WGs (1/CU), recurrent weights in LDS,
//                  manual device-scope flag barrier, 2 barriers/step
//   wd_gemm      : Y = H1 @ Wd + bd
// R1 fix: h-stage LDS tile was only half-initialized (NaN residue).
// R2 fix: conv_x produced xh[b][t][d] but zx0_gemm consumes xh[t][b][d]
//         -> conv_x now transposes to time-major. (absmax 0.58 root cause)
// ---------------------------------------------------------------------------

typedef _Float16 half8  __attribute__((ext_vector_type(8)));
typedef float    floatx4 __attribute__((ext_vector_type(4)));

// ws layout (bytes)
#define WREC_OFF   0UL            // [256 wg][3 mat][128 kc][16 c][8] f16 = 24 MiB
#define WX0_OFF    25165824UL     // [256 wg][64 kc][16 c][8] f16        = 4 MiB
#define WD_OFF     29360128UL     // [32 nt][128 kc][16 c][8] f16        = 1 MiB
#define XH_OFF     30408704UL     // [512 t][32 b][512 d] f16            = 16 MiB
#define ZX0_OFF    47185920UL     // [512 t][256 wg][32 m][16 c] f16     = 128 MiB
#define H0_OFF     181403648UL    // [32][1024] f16
#define H1_OFF     181469184UL    // [512 t][32 m][1024 k] f16           = 32 MiB
#define FLAGS_OFF  215023616UL    // [256] u32

__device__ __forceinline__ float fsig(float x){ return 1.0f/(1.0f + __expf(-x)); }
__device__ __forceinline__ float ftanhf(float x){
  float e = __expf(2.0f*fabsf(x));
  float r = 1.0f - 2.0f/(e + 1.0f);
  return copysignf(r, x);
}
__device__ __forceinline__ unsigned int umin4(unsigned int a, unsigned int b,
                                              unsigned int c, unsigned int d){
  unsigned int x = a < b ? a : b;
  unsigned int y = c < d ? c : d;
  return x < y ? x : y;
}

// ---------------- weight conversion ----------------------------------------
// recurrent weights: col = gate*1024 + wg*4 + jj, c = gate*4 + jj
__global__ void conv_wrec(const float* __restrict__ Wh0,
                          const float* __restrict__ Wx1,
                          const float* __restrict__ Wh1,
                          _Float16* __restrict__ out){
  int idx = blockIdx.x*256 + threadIdx.x;          // ((wg*3+mat)*128+kc)*16+c
  if (idx >= 256*3*128*16) return;
  int c  = idx & 15;
  int t1 = idx >> 4;
  int kc = t1 & 127;
  int t2 = t1 >> 7;
  int mat = t2 % 3;
  int wg  = t2 / 3;
  const float* W = (mat==0) ? Wh0 : (mat==1) ? Wx1 : Wh1;
  int col = (c>>2)*1024 + wg*4 + (c&3);
  _Float16* o = out + (size_t)idx*8;
  #pragma unroll
  for (int j=0;j<8;++j) o[j] = (_Float16)W[(kc*8+j)*4096 + col];
}

__global__ void conv_wx0(const float* __restrict__ W, _Float16* __restrict__ out){
  int idx = blockIdx.x*256 + threadIdx.x;          // ((wg*64+kc)*16+c)
  if (idx >= 256*64*16) return;
  int c  = idx & 15;
  int kc = (idx >> 4) & 63;
  int wg = idx >> 10;
  int col = (c>>2)*1024 + wg*4 + (c&3);
  _Float16* o = out + (size_t)idx*8;
  #pragma unroll
  for (int j=0;j<8;++j) o[j] = (_Float16)W[(kc*8+j)*4096 + col];
}

__global__ void conv_wd(const float* __restrict__ W, _Float16* __restrict__ out){
  int idx = blockIdx.x*256 + threadIdx.x;          // ((nt*128+kc)*16+c)
  if (idx >= 32*128*16) return;
  int c  = idx & 15;
  int kc = (idx >> 4) & 127;
  int nt = idx >> 11;
  int col = nt*16 + c;
  _Float16* o = out + (size_t)idx*8;
  #pragma unroll
  for (int j=0;j<8;++j) o[j] = (_Float16)W[(kc*8+j)*512 + col];
}

// x[b][t][d] fp32 -> xh[t*32+b][d] f16  (time-major rows for zx0_gemm)
__global__ void conv_x(const float* __restrict__ x, _Float16* __restrict__ xh){
  int idx = blockIdx.x*256 + threadIdx.x;          // [bt][dq], dq = d/4
  if (idx >= 2097152) return;
  int dq = idx & 127;
  int bt = idx >> 7;          // t*32 + b
  int b  = bt & 31;
  int t  = bt >> 5;
  float4 v = ((const float4*)x)[(size_t)(b*512 + t)*128 + dq];
  _Float16* o = xh + (size_t)idx*4;
  o[0]=(_Float16)v.x; o[1]=(_Float16)v.y; o[2]=(_Float16)v.z; o[3]=(_Float16)v.w;
}

// ---------------- Zx0 = x @ Wx0 + b0 ---------------------------------------
__global__ __launch_bounds__(64) void zx0_gemm(const _Float16* __restrict__ xh,
                                               const _Float16* __restrict__ wx0a,
                                               const float* __restrict__ b0,
                                               _Float16* __restrict__ zx0){
  int t   = blockIdx.x;        // 512
  int wgg = blockIdx.y;        // 64 (covers 4 wg slices)
  int l = threadIdx.x, q = l>>4, c = l&15;
  floatx4 acc[2][4];
  #pragma unroll
  for (int g=0; g<4; ++g){
    int wg = wgg*4+g;
    float bv = b0[(c>>2)*1024 + wg*4 + (c&3)];
    acc[0][g] = (floatx4){bv,bv,bv,bv};
    acc[1][g] = (floatx4){bv,bv,bv,bv};
  }
  #pragma unroll 4
  for (int ks=0; ks<16; ++ks){
    int kc = ks*4 + q;
    half8 a0 = *(const half8*)(xh + (t*32      + c)*512 + kc*8);
    half8 a1 = *(const half8*)(xh + (t*32 + 16 + c)*512 + kc*8);
    #pragma unroll
    for (int g=0; g<4; ++g){
      int wg = wgg*4+g;
      half8 b = *(const half8*)(wx0a + ((size_t)(wg*64 + kc)*16 + c)*8);
      acc[0][g] = __builtin_amdgcn_mfma_f32_16x16x32_f16(a0,b,acc[0][g],0,0,0);
      acc[1][g] = __builtin_amdgcn_mfma_f32_16x16x32_f16(a1,b,acc[1][g],0,0,0);
    }
  }
  #pragma unroll
  for (int g=0; g<4; ++g){
    int wg = wgg*4+g;
    #pragma unroll
    for (int mt=0; mt<2; ++mt)
      #pragma unroll
      for (int r=0;r<4;++r){
        int m = mt*16 + q*4 + r;
        zx0[((size_t)(t*256 + wg)*32 + m)*16 + c] = (_Float16)acc[mt][g][r];
      }
  }
}

// ---------------- persistent recurrent kernel ------------------------------
// LDS: w0 (Wh0) [128][16][8], w1 (Wx1), w2 (Wh1), hst [128][32][8]  = 160 KiB
__global__ __launch_bounds__(256, 1) void lstm_persist(
    const _Float16* __restrict__ wrec, const _Float16* __restrict__ zx0,
    const float* __restrict__ b1g, _Float16* __restrict__ h0b,
    _Float16* __restrict__ h1a, unsigned int* __restrict__ flags)
{
  extern __shared__ _Float16 lds[];
  _Float16* w0  = lds;            // 16384 halves
  _Float16* w1  = lds + 16384;
  _Float16* w2  = lds + 32768;
  _Float16* hst = lds + 49152;    // 32768 halves = [128 kc][32 m][8]

  const int wg = blockIdx.x, tid = threadIdx.x;
  const int wv = tid>>6, l = tid&63, q = l>>4, c = l&15;
  const int g = (c>>2);           // gate of own column
  const int mt = (wv < 2) ? wv : 0;

  { // stage this WG's weight slice: 98304 B = 6144 uint4
    const uint4* src = (const uint4*)(wrec + (size_t)wg*49152);
    uint4* dst = (uint4*)lds;
    for (int i=tid; i<6144; i+=256) dst[i] = src[i];
  }
  { // zero full h-stage (h0(-1) = 0): 4096 uint4
    uint4 z = make_uint4(0,0,0,0);
    uint4* dst = (uint4*)hst;
    for (int i=tid; i<4096; i+=256) dst[i] = z;
  }
  float c0[4] = {0,0,0,0}, c1[4] = {0,0,0,0};
  const float b1v = b1g[g*1024 + wg*4 + (c&3)];
  __syncthreads();

  for (int t=0; t<512; ++t){
    // ---------- phase A: z0 = Zx0[t] + h0(t-1)@Wh0 ; h0(t) ----------
    if (wv < 2){
      const _Float16* zsrc = zx0 + ((size_t)(t*256 + wg)*32 + mt*16 + q*4)*16 + c;
      float zx0v0 = (float)zsrc[0],  zx0v1 = (float)zsrc[16];
      float zx0v2 = (float)zsrc[32], zx0v3 = (float)zsrc[48];
      floatx4 acc = (floatx4){0.f,0.f,0.f,0.f};
      #pragma unroll
      for (int ks=0; ks<32; ++ks){
        int kc = ks*4 + q;
        half8 a = *(const half8*)(hst + (kc*32 + mt*16 + c)*8);
        half8 b = *(const half8*)(w0  + (kc*16 + c)*8);
        acc = __builtin_amdgcn_mfma_f32_16x16x32_f16(a,b,acc,0,0,0);
      }
      acc[0]+=zx0v0; acc[1]+=zx0v1; acc[2]+=zx0v2; acc[3]+=zx0v3;
      // gate exchange: lanes l, l^4, l^8, l^12 hold gates g, g^1, g^2, g^3
      #pragma unroll
      for (int r=0;r<4;++r){
        float v0 = acc[r];
        float v1 = __shfl_xor(v0, 4, 64);
        float v2 = __shfl_xor(v0, 8, 64);
        float v3 = __shfl_xor(v1, 8, 64);
        float zi = (g==0)?v0:(g==1)?v1:(g==2)?v2:v3;
        float zf = (g==0)?v1:(g==1)?v0:(g==2)?v3:v2;
        float zg = (g==0)?v2:(g==1)?v3:(g==2)?v0:v1;
        float zo = (g==0)?v3:(g==1)?v2:(g==2)?v1:v0;
        float cn = fsig(zf)*c0[r] + fsig(zi)*ftanhf(zg);
        c0[r] = cn;
        float hv = fsig(zo)*ftanhf(cn);
        if (g==0) h0b[(mt*16 + q*4 + r)*1024 + wg*4 + c] = (_Float16)hv;
      }
    }
    __syncthreads();
    if (tid==0){
      __builtin_amdgcn_fence(__ATOMIC_RELEASE, "agent");
      __hip_atomic_store(flags+wg, (unsigned)(2*t+1), __ATOMIC_RELAXED,
                         __HIP_MEMORY_SCOPE_AGENT);
    }
    if (wv==0){
      unsigned tgt = (unsigned)(2*t+1);
      for (;;){
        unsigned m0=__hip_atomic_load(flags+l,    __ATOMIC_RELAXED,__HIP_MEMORY_SCOPE_AGENT);
        unsigned m1=__hip_atomic_load(flags+64+l, __ATOMIC_RELAXED,__HIP_MEMORY_SCOPE_AGENT);
        unsigned m2=__hip_atomic_load(flags+128+l,__ATOMIC_RELAXED,__HIP_MEMORY_SCOPE_AGENT);
        unsigned m3=__hip_atomic_load(flags+192+l,__ATOMIC_RELAXED,__HIP_MEMORY_SCOPE_AGENT);
        if (__all(umin4(m0,m1,m2,m3) >= tgt)) break;
        __builtin_amdgcn_s_sleep(1);
      }
    }
    __syncthreads();
    __builtin_amdgcn_fence(__ATOMIC_ACQUIRE, "agent");

    // ---------- phase B: z1 = h1(t-1)@Wh1 + h0(t)@Wx1 + b1 ; h1(t) ----------
    if (t == 0){
      uint4 z = make_uint4(0,0,0,0);
      uint4* dst = (uint4*)hst;
      for (int i=tid; i<4096; i+=256) dst[i] = z;
    } else {
      // stage h1(t-1): src is [32 m][128 kc] uint4, dst hst linear [128 kc][32 m]
      const uint4* src = (const uint4*)(h1a + (size_t)(t-1)*32768);
      uint4* dst = (uint4*)hst;
      for (int i=tid; i<4096; i+=256){
        int kc = i>>5, m = i&31;
        dst[i] = src[m*128 + kc];
      }
    }
    __syncthreads();
    floatx4 acc1 = (floatx4){b1v,b1v,b1v,b1v};
    if (wv < 2){
      #pragma unroll
      for (int ks=0; ks<32; ++ks){
        int kc = ks*4 + q;
        half8 a = *(const half8*)(hst + (kc*32 + mt*16 + c)*8);
        half8 b = *(const half8*)(w2  + (kc*16 + c)*8);
        acc1 = __builtin_amdgcn_mfma_f32_16x16x32_f16(a,b,acc1,0,0,0);
      }
    }
    __syncthreads();
    { // stage h0(t)
      const uint4* src = (const uint4*)h0b;
      uint4* dst = (uint4*)hst;
      for (int i=tid; i<4096; i+=256){
        int kc = i>>5, m = i&31;
        dst[i] = src[m*128 + kc];
      }
    }
    __syncthreads();
    if (wv < 2){
      #pragma unroll
      for (int ks=0; ks<32; ++ks){
        int kc = ks*4 + q;
        half8 a = *(const half8*)(hst + (kc*32 + mt*16 + c)*8);
        half8 b = *(const half8*)(w1  + (kc*16 + c)*8);
        acc1 = __builtin_amdgcn_mfma_f32_16x16x32_f16(a,b,acc1,0,0,0);
      }
      #pragma unroll
      for (int r=0;r<4;++r){
        float v0 = acc1[r];
        float v1 = __shfl_xor(v0, 4, 64);
        float v2 = __shfl_xor(v0, 8, 64);
        float v3 = __shfl_xor(v1, 8, 64);
        float zi = (g==0)?v0:(g==1)?v1:(g==2)?v2:v3;
        float zf = (g==0)?v1:(g==1)?v0:(g==2)?v3:v2;
        float zg = (g==0)?v2:(g==1)?v3:(g==2)?v0:v1;
        float zo = (g==0)?v3:(g==1)?v2:(g==2)?v1:v0;
        float cn = fsig(zf)*c1[r] + fsig(zi)*ftanhf(zg);
        c1[r] = cn;
        float hv = fsig(zo)*ftanhf(cn);
        if (g==0) h1a[(size_t)t*32768 + (mt*16 + q*4 + r)*1024 + wg*4 + c] = (_Float16)hv;
      }
    }
    __syncthreads();
    if (tid==0){
      __builtin_amdgcn_fence(__ATOMIC_RELEASE, "agent");
      __hip_atomic_store(flags+wg, (unsigned)(2*t+2), __ATOMIC_RELAXED,
                         __HIP_MEMORY_SCOPE_AGENT);
    }
    if (wv==0){
      unsigned tgt = (unsigned)(2*t+2);
      for (;;){
        unsigned m0=__hip_atomic_load(flags+l,    __ATOMIC_RELAXED,__HIP_MEMORY_SCOPE_AGENT);
        unsigned m1=__hip_atomic_load(flags+64+l, __ATOMIC_RELAXED,__HIP_MEMORY_SCOPE_AGENT);
        unsigned m2=__hip_atomic_load(flags+128+l,__ATOMIC_RELAXED,__HIP_MEMORY_SCOPE_AGENT);
        unsigned m3=__hip_atomic_load(flags+192+l,__ATOMIC_RELAXED,__HIP_MEMORY_SCOPE_AGENT);
        if (__all(umin4(m0,m1,m2,m3) >= tgt)) break;
        __builtin_amdgcn_s_sleep(1);
      }
    }
    __syncthreads();
    __builtin_amdgcn_fence(__ATOMIC_ACQUIRE, "agent");
    // hst now holds h0(t) -> used directly by phase A of step t+1
  }
}

// ---------------- Y = H1 @ Wd + bd -----------------------------------------
__global__ __launch_bounds__(256) void wd_gemm(const _Float16* __restrict__ h1a,
                                               const _Float16* __restrict__ wda,
                                               const float* __restrict__ bd,
                                               float* __restrict__ y){
  int mb = blockIdx.x;   // 512 blocks of 32 rows (rows = t*32+b)
  int nb = blockIdx.y;   // 4 blocks of 128 cols
  int tid = threadIdx.x, wv = tid>>6, l = tid&63, q = l>>4, c = l&15;
  int mt = wv & 1, nh = wv >> 1;
  floatx4 acc[4];
  #pragma unroll
  for (int gg=0; gg<4; ++gg) acc[gg] = (floatx4){0.f,0.f,0.f,0.f};
  const _Float16* arow = h1a + (size_t)(mb*32 + mt*16 + c)*1024;
  #pragma unroll 4
  for (int ks=0; ks<32; ++ks){
    int kc = ks*4 + q;
    half8 a = *(const half8*)(arow + kc*8);
    #pragma unroll
    for (int gg=0; gg<4; ++gg){
      int nt = nb*8 + nh*4 + gg;
      half8 b = *(const half8*)(wda + ((size_t)(nt*128 + kc)*16 + c)*8);
      acc[gg] = __builtin_amdgcn_mfma_f32_16x16x32_f16(a,b,acc[gg],0,0,0);
    }
  }
  #pragma unroll
  for (int gg=0; gg<4; ++gg){
    int o = nb*128 + nh*64 + gg*16 + c;
    float bdv = bd[o];
    #pragma unroll
    for (int r=0;r<4;++r){
      int row = mb*32 + mt*16 + q*4 + r;
      int tt = row >> 5, bb = row & 31;
      y[(size_t)bb*262144 + tt*512 + o] = acc[gg][r] + bdv;
    }
  }
}

// ---------------------------------------------------------------------------
extern "C" void kernel_launch(void* const* d_in, const int* in_sizes, int n_in,
                              void* d_out, int out_size, void* d_ws, size_t ws_size,
                              hipStream_t stream){
  const float* x   = (const float*)d_in[0];
  const float* Wx0 = (const float*)d_in[1];
  const float* Wh0 = (const float*)d_in[2];
  const float* b0  = (const float*)d_in[3];
  const float* Wx1 = (const float*)d_in[4];
  const float* Wh1 = (const float*)d_in[5];
  const float* b1  = (const float*)d_in[6];
  const float* Wd  = (const float*)d_in[7];
  const float* bd  = (const float*)d_in[8];
  float* y = (float*)d_out;
  char* ws = (char*)d_ws;

  _Float16* wrec = (_Float16*)(ws + WREC_OFF);
  _Float16* wx0a = (_Float16*)(ws + WX0_OFF);
  _Float16* wda  = (_Float16*)(ws + WD_OFF);
  _Float16* xh   = (_Float16*)(ws + XH_OFF);
  _Float16* zx0  = (_Float16*)(ws + ZX0_OFF);
  _Float16* h0b  = (_Float16*)(ws + H0_OFF);
  _Float16* h1a  = (_Float16*)(ws + H1_OFF);
  unsigned int* flags = (unsigned int*)(ws + FLAGS_OFF);

  hipMemsetAsync(flags, 0, 1024, stream);
  conv_wrec<<<dim3(6144), dim3(256), 0, stream>>>(Wh0, Wx1, Wh1, wrec);
  conv_wx0 <<<dim3(1024), dim3(256), 0, stream>>>(Wx0, wx0a);
  conv_wd  <<<dim3(256),  dim3(256), 0, stream>>>(Wd, wda);
  conv_x   <<<dim3(8192), dim3(256), 0, stream>>>(x, xh);
  zx0_gemm <<<dim3(512,64), dim3(64), 0, stream>>>(xh, wx0a, b0, zx0);
  hipFuncSetAttribute((const void*)lstm_persist,
                      hipFuncAttributeMaxDynamicSharedMemorySize, 163840);
  lstm_persist<<<dim3(256), dim3(256), 163840, stream>>>(wrec, zx0, b1, h0b, h1a, flags);
  wd_gemm  <<<dim3(512,4), dim3(256), 0, stream>>>(h1a, wda, bd, y);
}

// Round 4
// 14807.387 us; speedup vs baseline: 1.5657x; 1.5657x over previous
//
#include <hip/hip_runtime.h>

// ---------------------------------------------------------------------------
// SimpleLSTM: 2-layer LSTM (B=32,T=512,D=512,H=1024) + output proj (O=512).
//   conv kernels : fp32 -> f16, weights rearranged into MFMA B-frag order
//   zx0_gemm     : Zx0[t][wg][m][c] = x@Wx0 + b0  (parallel over all T)
//   lstm_persist : 256 persistent WGs (1/CU), recurrent weights in LDS
//   wd_gemm      : Y = H1 @ Wd + bd
// R1: h-stage LDS tile fully initialized (NaN fix).
// R2: conv_x transposes to time-major (correctness fix).
// R4: barrier rework — all-to-all 1KiB flag polling (O(N^2) reads, ~22us per
//     barrier) replaced by 16-group tree arrival + single-word epoch
//     broadcast; 2 barriers/step -> 1 (h1 visibility piggybacks on the A->B
//     barrier; h0b double-buffered on t&1 to kill the WAR hazard).
// ---------------------------------------------------------------------------

typedef _Float16 half8  __attribute__((ext_vector_type(8)));
typedef float    floatx4 __attribute__((ext_vector_type(4)));

// ws layout (bytes)
#define WREC_OFF   0UL            // [256 wg][3 mat][128 kc][16 c][8] f16 = 24 MiB
#define WX0_OFF    25165824UL     // [256 wg][64 kc][16 c][8] f16        = 4 MiB
#define WD_OFF     29360128UL     // [32 nt][128 kc][16 c][8] f16        = 1 MiB
#define XH_OFF     30408704UL     // [512 t][32 b][512 d] f16            = 16 MiB
#define ZX0_OFF    47185920UL     // [512 t][256 wg][32 m][16 c] f16     = 128 MiB
#define H0_OFF     181403648UL    // [2][32][1024] f16 (double-buffered)
#define H1_OFF     181534720UL    // [512 t][32 m][1024 k] f16           = 32 MiB
#define FLAGS_OFF  215089152UL    // 8 KiB: gcnt[16] @256B stride, root, epoch

__device__ __forceinline__ float fsig(float x){ return 1.0f/(1.0f + __expf(-x)); }
__device__ __forceinline__ float ftanhf(float x){
  float e = __expf(2.0f*fabsf(x));
  float r = 1.0f - 2.0f/(e + 1.0f);
  return copysignf(r, x);
}

// ---------------- weight conversion ----------------------------------------
// recurrent weights: col = gate*1024 + wg*4 + jj, c = gate*4 + jj
__global__ void conv_wrec(const float* __restrict__ Wh0,
                          const float* __restrict__ Wx1,
                          const float* __restrict__ Wh1,
                          _Float16* __restrict__ out){
  int idx = blockIdx.x*256 + threadIdx.x;          // ((wg*3+mat)*128+kc)*16+c
  if (idx >= 256*3*128*16) return;
  int c  = idx & 15;
  int t1 = idx >> 4;
  int kc = t1 & 127;
  int t2 = t1 >> 7;
  int mat = t2 % 3;
  int wg  = t2 / 3;
  const float* W = (mat==0) ? Wh0 : (mat==1) ? Wx1 : Wh1;
  int col = (c>>2)*1024 + wg*4 + (c&3);
  _Float16* o = out + (size_t)idx*8;
  #pragma unroll
  for (int j=0;j<8;++j) o[j] = (_Float16)W[(kc*8+j)*4096 + col];
}

__global__ void conv_wx0(const float* __restrict__ W, _Float16* __restrict__ out){
  int idx = blockIdx.x*256 + threadIdx.x;          // ((wg*64+kc)*16+c)
  if (idx >= 256*64*16) return;
  int c  = idx & 15;
  int kc = (idx >> 4) & 63;
  int wg = idx >> 10;
  int col = (c>>2)*1024 + wg*4 + (c&3);
  _Float16* o = out + (size_t)idx*8;
  #pragma unroll
  for (int j=0;j<8;++j) o[j] = (_Float16)W[(kc*8+j)*4096 + col];
}

__global__ void conv_wd(const float* __restrict__ W, _Float16* __restrict__ out){
  int idx = blockIdx.x*256 + threadIdx.x;          // ((nt*128+kc)*16+c)
  if (idx >= 32*128*16) return;
  int c  = idx & 15;
  int kc = (idx >> 4) & 127;
  int nt = idx >> 11;
  int col = nt*16 + c;
  _Float16* o = out + (size_t)idx*8;
  #pragma unroll
  for (int j=0;j<8;++j) o[j] = (_Float16)W[(kc*8+j)*512 + col];
}

// x[b][t][d] fp32 -> xh[t*32+b][d] f16  (time-major rows for zx0_gemm)
__global__ void conv_x(const float* __restrict__ x, _Float16* __restrict__ xh){
  int idx = blockIdx.x*256 + threadIdx.x;          // [bt][dq], dq = d/4
  if (idx >= 2097152) return;
  int dq = idx & 127;
  int bt = idx >> 7;          // t*32 + b
  int b  = bt & 31;
  int t  = bt >> 5;
  float4 v = ((const float4*)x)[(size_t)(b*512 + t)*128 + dq];
  _Float16* o = xh + (size_t)idx*4;
  o[0]=(_Float16)v.x; o[1]=(_Float16)v.y; o[2]=(_Float16)v.z; o[3]=(_Float16)v.w;
}

// ---------------- Zx0 = x @ Wx0 + b0 ---------------------------------------
__global__ __launch_bounds__(64) void zx0_gemm(const _Float16* __restrict__ xh,
                                               const _Float16* __restrict__ wx0a,
                                               const float* __restrict__ b0,
                                               _Float16* __restrict__ zx0){
  int t   = blockIdx.x;        // 512
  int wgg = blockIdx.y;        // 64 (covers 4 wg slices)
  int l = threadIdx.x, q = l>>4, c = l&15;
  floatx4 acc[2][4];
  #pragma unroll
  for (int g=0; g<4; ++g){
    int wg = wgg*4+g;
    float bv = b0[(c>>2)*1024 + wg*4 + (c&3)];
    acc[0][g] = (floatx4){bv,bv,bv,bv};
    acc[1][g] = (floatx4){bv,bv,bv,bv};
  }
  #pragma unroll 4
  for (int ks=0; ks<16; ++ks){
    int kc = ks*4 + q;
    half8 a0 = *(const half8*)(xh + (t*32      + c)*512 + kc*8);
    half8 a1 = *(const half8*)(xh + (t*32 + 16 + c)*512 + kc*8);
    #pragma unroll
    for (int g=0; g<4; ++g){
      int wg = wgg*4+g;
      half8 b = *(const half8*)(wx0a + ((size_t)(wg*64 + kc)*16 + c)*8);
      acc[0][g] = __builtin_amdgcn_mfma_f32_16x16x32_f16(a0,b,acc[0][g],0,0,0);
      acc[1][g] = __builtin_amdgcn_mfma_f32_16x16x32_f16(a1,b,acc[1][g],0,0,0);
    }
  }
  #pragma unroll
  for (int g=0; g<4; ++g){
    int wg = wgg*4+g;
    #pragma unroll
    for (int mt=0; mt<2; ++mt)
      #pragma unroll
      for (int r=0;r<4;++r){
        int m = mt*16 + q*4 + r;
        zx0[((size_t)(t*256 + wg)*32 + m)*16 + c] = (_Float16)acc[mt][g][r];
      }
  }
}

// ---------------- persistent recurrent kernel ------------------------------
// LDS: w0 (Wh0) [128][16][8], w1 (Wx1), w2 (Wh1), hst [128][32][8]  = 160 KiB
__global__ __launch_bounds__(256, 1) void lstm_persist(
    const _Float16* __restrict__ wrec, const _Float16* __restrict__ zx0,
    const float* __restrict__ b1g, _Float16* __restrict__ h0b,
    _Float16* __restrict__ h1a, unsigned int* __restrict__ flags)
{
  extern __shared__ _Float16 lds[];
  _Float16* w0  = lds;            // 16384 halves
  _Float16* w1  = lds + 16384;
  _Float16* w2  = lds + 32768;
  _Float16* hst = lds + 49152;    // 32768 halves = [128 kc][32 m][8]

  const int wg = blockIdx.x, tid = threadIdx.x;
  const int wv = tid>>6, l = tid&63, q = l>>4, c = l&15;
  const int g = (c>>2);           // gate of own column
  const int mt = (wv < 2) ? wv : 0;

  unsigned int* gcnt  = flags + (wg>>4)*64;   // 16 groups, 256B apart
  unsigned int* root  = flags + 1024;         // own line
  unsigned int* epoch = flags + 1088;         // own line

  { // stage this WG's weight slice: 98304 B = 6144 uint4
    const uint4* src = (const uint4*)(wrec + (size_t)wg*49152);
    uint4* dst = (uint4*)lds;
    for (int i=tid; i<6144; i+=256) dst[i] = src[i];
  }
  { // zero full h-stage (h0(-1) = 0): 4096 uint4
    uint4 z = make_uint4(0,0,0,0);
    uint4* dst = (uint4*)hst;
    for (int i=tid; i<4096; i+=256) dst[i] = z;
  }
  float c0[4] = {0,0,0,0}, c1[4] = {0,0,0,0};
  const float b1v = b1g[g*1024 + wg*4 + (c&3)];
  __syncthreads();

  for (int t=0; t<512; ++t){
    // ---------- phase A: z0 = Zx0[t] + h0(t-1)@Wh0 ; h0(t) ----------
    if (wv < 2){
      const _Float16* zsrc = zx0 + ((size_t)(t*256 + wg)*32 + mt*16 + q*4)*16 + c;
      float zx0v0 = (float)zsrc[0],  zx0v1 = (float)zsrc[16];
      float zx0v2 = (float)zsrc[32], zx0v3 = (float)zsrc[48];
      floatx4 acc = (floatx4){0.f,0.f,0.f,0.f};
      #pragma unroll
      for (int ks=0; ks<32; ++ks){
        int kc = ks*4 + q;
        half8 a = *(const half8*)(hst + (kc*32 + mt*16 + c)*8);
        half8 b = *(const half8*)(w0  + (kc*16 + c)*8);
        acc = __builtin_amdgcn_mfma_f32_16x16x32_f16(a,b,acc,0,0,0);
      }
      acc[0]+=zx0v0; acc[1]+=zx0v1; acc[2]+=zx0v2; acc[3]+=zx0v3;
      // gate exchange: lanes l, l^4, l^8, l^12 hold gates g, g^1, g^2, g^3
      _Float16* h0dst = h0b + (size_t)(t&1)*32768;
      #pragma unroll
      for (int r=0;r<4;++r){
        float v0 = acc[r];
        float v1 = __shfl_xor(v0, 4, 64);
        float v2 = __shfl_xor(v0, 8, 64);
        float v3 = __shfl_xor(v1, 8, 64);
        float zi = (g==0)?v0:(g==1)?v1:(g==2)?v2:v3;
        float zf = (g==0)?v1:(g==1)?v0:(g==2)?v3:v2;
        float zg = (g==0)?v2:(g==1)?v3:(g==2)?v0:v1;
        float zo = (g==0)?v3:(g==1)?v2:(g==2)?v1:v0;
        float cn = fsig(zf)*c0[r] + fsig(zi)*ftanhf(zg);
        c0[r] = cn;
        float hv = fsig(zo)*ftanhf(cn);
        if (g==0) h0dst[(mt*16 + q*4 + r)*1024 + wg*4 + c] = (_Float16)hv;
      }
    }
    __syncthreads();
    // ---------- single device barrier per step (tree arrival + epoch) ----
    // Guarantees: h0(t) from all WGs visible AND every WG finished B(t-1)
    // (so h1(t-1) is visible too).
    if (tid==0){
      __builtin_amdgcn_fence(__ATOMIC_RELEASE, "agent");
      unsigned tgt = 16u*(unsigned)(t+1);
      unsigned o = __hip_atomic_fetch_add(gcnt, 1u, __ATOMIC_RELAXED,
                                          __HIP_MEMORY_SCOPE_AGENT);
      if (o == tgt - 1u){
        unsigned r = __hip_atomic_fetch_add(root, 1u, __ATOMIC_RELAXED,
                                            __HIP_MEMORY_SCOPE_AGENT);
        if (r == tgt - 1u)
          __hip_atomic_store(epoch, (unsigned)(t+1), __ATOMIC_RELAXED,
                             __HIP_MEMORY_SCOPE_AGENT);
      }
    }
    if (wv==0){
      unsigned tgt = (unsigned)(t+1);
      while (__hip_atomic_load(epoch, __ATOMIC_RELAXED,
                               __HIP_MEMORY_SCOPE_AGENT) < tgt)
        __builtin_amdgcn_s_sleep(1);
    }
    __syncthreads();
    __builtin_amdgcn_fence(__ATOMIC_ACQUIRE, "agent");

    // ---------- phase B: z1 = h1(t-1)@Wh1 + h0(t)@Wx1 + b1 ; h1(t) ----------
    if (t == 0){
      uint4 z = make_uint4(0,0,0,0);
      uint4* dst = (uint4*)hst;
      for (int i=tid; i<4096; i+=256) dst[i] = z;
    } else {
      // stage h1(t-1): src is [32 m][128 kc] uint4, dst hst linear [128 kc][32 m]
      const uint4* src = (const uint4*)(h1a + (size_t)(t-1)*32768);
      uint4* dst = (uint4*)hst;
      for (int i=tid; i<4096; i+=256){
        int kc = i>>5, m = i&31;
        dst[i] = src[m*128 + kc];
      }
    }
    __syncthreads();
    floatx4 acc1 = (floatx4){b1v,b1v,b1v,b1v};
    if (wv < 2){
      #pragma unroll
      for (int ks=0; ks<32; ++ks){
        int kc = ks*4 + q;
        half8 a = *(const half8*)(hst + (kc*32 + mt*16 + c)*8);
        half8 b = *(const half8*)(w2  + (kc*16 + c)*8);
        acc1 = __builtin_amdgcn_mfma_f32_16x16x32_f16(a,b,acc1,0,0,0);
      }
    }
    __syncthreads();
    { // stage h0(t) from current parity buffer
      const uint4* src = (const uint4*)(h0b + (size_t)(t&1)*32768);
      uint4* dst = (uint4*)hst;
      for (int i=tid; i<4096; i+=256){
        int kc = i>>5, m = i&31;
        dst[i] = src[m*128 + kc];
      }
    }
    __syncthreads();
    if (wv < 2){
      #pragma unroll
      for (int ks=0; ks<32; ++ks){
        int kc = ks*4 + q;
        half8 a = *(const half8*)(hst + (kc*32 + mt*16 + c)*8);
        half8 b = *(const half8*)(w1  + (kc*16 + c)*8);
        acc1 = __builtin_amdgcn_mfma_f32_16x16x32_f16(a,b,acc1,0,0,0);
      }
      #pragma unroll
      for (int r=0;r<4;++r){
        float v0 = acc1[r];
        float v1 = __shfl_xor(v0, 4, 64);
        float v2 = __shfl_xor(v0, 8, 64);
        float v3 = __shfl_xor(v1, 8, 64);
        float zi = (g==0)?v0:(g==1)?v1:(g==2)?v2:v3;
        float zf = (g==0)?v1:(g==1)?v0:(g==2)?v3:v2;
        float zg = (g==0)?v2:(g==1)?v3:(g==2)?v0:v1;
        float zo = (g==0)?v3:(g==1)?v2:(g==2)?v1:v0;
        float cn = fsig(zf)*c1[r] + fsig(zi)*ftanhf(zg);
        c1[r] = cn;
        float hv = fsig(zo)*ftanhf(cn);
        if (g==0) h1a[(size_t)t*32768 + (mt*16 + q*4 + r)*1024 + wg*4 + c] = (_Float16)hv;
      }
    }
    __syncthreads();
    // hst holds h0(t) -> used directly by phase A of step t+1; h1(t) writes
    // become visible to step t+1's phase B via the next step's barrier.
  }
}

// ---------------- Y = H1 @ Wd + bd -----------------------------------------
__global__ __launch_bounds__(256) void wd_gemm(const _Float16* __restrict__ h1a,
                                               const _Float16* __restrict__ wda,
                                               const float* __restrict__ bd,
                                               float* __restrict__ y){
  int mb = blockIdx.x;   // 512 blocks of 32 rows (rows = t*32+b)
  int nb = blockIdx.y;   // 4 blocks of 128 cols
  int tid = threadIdx.x, wv = tid>>6, l = tid&63, q = l>>4, c = l&15;
  int mt = wv & 1, nh = wv >> 1;
  floatx4 acc[4];
  #pragma unroll
  for (int gg=0; gg<4; ++gg) acc[gg] = (floatx4){0.f,0.f,0.f,0.f};
  const _Float16* arow = h1a + (size_t)(mb*32 + mt*16 + c)*1024;
  #pragma unroll 4
  for (int ks=0; ks<32; ++ks){
    int kc = ks*4 + q;
    half8 a = *(const half8*)(arow + kc*8);
    #pragma unroll
    for (int gg=0; gg<4; ++gg){
      int nt = nb*8 + nh*4 + gg;
      half8 b = *(const half8*)(wda + ((size_t)(nt*128 + kc)*16 + c)*8);
      acc[gg] = __builtin_amdgcn_mfma_f32_16x16x32_f16(a,b,acc[gg],0,0,0);
    }
  }
  #pragma unroll
  for (int gg=0; gg<4; ++gg){
    int o = nb*128 + nh*64 + gg*16 + c;
    float bdv = bd[o];
    #pragma unroll
    for (int r=0;r<4;++r){
      int row = mb*32 + mt*16 + q*4 + r;
      int tt = row >> 5, bb = row & 31;
      y[(size_t)bb*262144 + tt*512 + o] = acc[gg][r] + bdv;
    }
  }
}

// ---------------------------------------------------------------------------
extern "C" void kernel_launch(void* const* d_in, const int* in_sizes, int n_in,
                              void* d_out, int out_size, void* d_ws, size_t ws_size,
                              hipStream_t stream){
  const float* x   = (const float*)d_in[0];
  const float* Wx0 = (const float*)d_in[1];
  const float* Wh0 = (const float*)d_in[2];
  const float* b0  = (const float*)d_in[3];
  const float* Wx1 = (const float*)d_in[4];
  const float* Wh1 = (const float*)d_in[5];
  const float* b1  = (const float*)d_in[6];
  const float* Wd  = (const float*)d_in[7];
  const float* bd  = (const float*)d_in[8];
  float* y = (float*)d_out;
  char* ws = (char*)d_ws;

  _Float16* wrec = (_Float16*)(ws + WREC_OFF);
  _Float16* wx0a = (_Float16*)(ws + WX0_OFF);
  _Float16* wda  = (_Float16*)(ws + WD_OFF);
  _Float16* xh   = (_Float16*)(ws + XH_OFF);
  _Float16* zx0  = (_Float16*)(ws + ZX0_OFF);
  _Float16* h0b  = (_Float16*)(ws + H0_OFF);
  _Float16* h1a  = (_Float16*)(ws + H1_OFF);
  unsigned int* flags = (unsigned int*)(ws + FLAGS_OFF);

  hipMemsetAsync(flags, 0, 8192, stream);
  conv_wrec<<<dim3(6144), dim3(256), 0, stream>>>(Wh0, Wx1, Wh1, wrec);
  conv_wx0 <<<dim3(1024), dim3(256), 0, stream>>>(Wx0, wx0a);
  conv_wd  <<<dim3(256),  dim3(256), 0, stream>>>(Wd, wda);
  conv_x   <<<dim3(8192), dim3(256), 0, stream>>>(x, xh);
  zx0_gemm <<<dim3(512,64), dim3(64), 0, stream>>>(xh, wx0a, b0, zx0);
  hipFuncSetAttribute((const void*)lstm_persist,
                      hipFuncAttributeMaxDynamicSharedMemorySize, 163840);
  lstm_persist<<<dim3(256), dim3(256), 163840, stream>>>(wrec, zx0, b1, h0b, h1a, flags);
  wd_gemm  <<<dim3(512,4), dim3(256), 0, stream>>>(h1a, wda, bd, y);
}

// Round 5
// 8656.113 us; speedup vs baseline: 2.6783x; 1.7106x over previous
//
#include <hip/hip_runtime.h>

// ---------------------------------------------------------------------------
// SimpleLSTM: 2-layer LSTM (B=32,T=512,D=512,H=1024) + output proj (O=512).
//   conv kernels : fp32 -> f16, weights rearranged into MFMA B-frag order
//   zx0_gemm     : Zx0[t][wg][m][c] = x@Wx0 + b0  (parallel over all T)
//   lstm_persist : 256 persistent WGs (1/CU), recurrent weights in LDS
//   wd_gemm      : Y = H1 @ Wd + bd
// R1: h-stage LDS tile fully initialized (NaN fix).
// R2: conv_x transposes to time-major (correctness fix).
// R4: tree barrier + 1 barrier/step (22.7 -> 14.5 ms).
// R5: fence diet. h-exchange via agent-scope relaxed atomic dword stores
//     (uncached, straight to LLC) -> release fence (buffer_wbl2) removed;
//     __syncthreads' vmcnt drain orders stores before the arrival RMW.
//     Acquire (buffer_inv) kept so cached h reads refetch fresh LLC data,
//     shared per-XCD. LDS h-staging removed: MFMA A-frags are contiguous
//     16B row slices, loaded directly from global (L2-cached). Barrier:
//     32 groups x 8, leaders store gdone[g], every WG scans 32 words.
//     Block 128 (no idle waves), 4-way/2+2-way MFMA chain ILP.
// ---------------------------------------------------------------------------

typedef _Float16 half8  __attribute__((ext_vector_type(8)));
typedef float    floatx4 __attribute__((ext_vector_type(4)));

// ws layout (bytes)
#define WREC_OFF   0UL            // [256 wg][3 mat][128 kc][16 c][8] f16 = 24 MiB
#define WX0_OFF    25165824UL     // [256 wg][64 kc][16 c][8] f16        = 4 MiB
#define WD_OFF     29360128UL     // [32 nt][128 kc][16 c][8] f16        = 1 MiB
#define XH_OFF     30408704UL     // [512 t][32 b][512 d] f16            = 16 MiB
#define ZX0_OFF    47185920UL     // [512 t][256 wg][32 m][16 c] f16     = 128 MiB
#define H0_OFF     181403648UL    // [2][32][1024] f16 (double-buffered)
#define H1_OFF     181534720UL    // [512 t][32 m][1024 k] f16           = 32 MiB
#define FLAGS_OFF  215089152UL    // 8 KiB: gcnt[32] @128B stride, gdone[32]

__device__ __forceinline__ float fsig(float x){ return 1.0f/(1.0f + __expf(-x)); }
__device__ __forceinline__ float ftanhf(float x){
  float e = __expf(2.0f*fabsf(x));
  float r = 1.0f - 2.0f/(e + 1.0f);
  return copysignf(r, x);
}

// ---------------- weight conversion ----------------------------------------
// recurrent weights: col = gate*1024 + wg*4 + jj, c = gate*4 + jj
__global__ void conv_wrec(const float* __restrict__ Wh0,
                          const float* __restrict__ Wx1,
                          const float* __restrict__ Wh1,
                          _Float16* __restrict__ out){
  int idx = blockIdx.x*256 + threadIdx.x;          // ((wg*3+mat)*128+kc)*16+c
  if (idx >= 256*3*128*16) return;
  int c  = idx & 15;
  int t1 = idx >> 4;
  int kc = t1 & 127;
  int t2 = t1 >> 7;
  int mat = t2 % 3;
  int wg  = t2 / 3;
  const float* W = (mat==0) ? Wh0 : (mat==1) ? Wx1 : Wh1;
  int col = (c>>2)*1024 + wg*4 + (c&3);
  _Float16* o = out + (size_t)idx*8;
  #pragma unroll
  for (int j=0;j<8;++j) o[j] = (_Float16)W[(kc*8+j)*4096 + col];
}

__global__ void conv_wx0(const float* __restrict__ W, _Float16* __restrict__ out){
  int idx = blockIdx.x*256 + threadIdx.x;          // ((wg*64+kc)*16+c)
  if (idx >= 256*64*16) return;
  int c  = idx & 15;
  int kc = (idx >> 4) & 63;
  int wg = idx >> 10;
  int col = (c>>2)*1024 + wg*4 + (c&3);
  _Float16* o = out + (size_t)idx*8;
  #pragma unroll
  for (int j=0;j<8;++j) o[j] = (_Float16)W[(kc*8+j)*4096 + col];
}

__global__ void conv_wd(const float* __restrict__ W, _Float16* __restrict__ out){
  int idx = blockIdx.x*256 + threadIdx.x;          // ((nt*128+kc)*16+c)
  if (idx >= 32*128*16) return;
  int c  = idx & 15;
  int kc = (idx >> 4) & 127;
  int nt = idx >> 11;
  int col = nt*16 + c;
  _Float16* o = out + (size_t)idx*8;
  #pragma unroll
  for (int j=0;j<8;++j) o[j] = (_Float16)W[(kc*8+j)*512 + col];
}

// x[b][t][d] fp32 -> xh[t*32+b][d] f16  (time-major rows for zx0_gemm)
__global__ void conv_x(const float* __restrict__ x, _Float16* __restrict__ xh){
  int idx = blockIdx.x*256 + threadIdx.x;          // [bt][dq], dq = d/4
  if (idx >= 2097152) return;
  int dq = idx & 127;
  int bt = idx >> 7;          // t*32 + b
  int b  = bt & 31;
  int t  = bt >> 5;
  float4 v = ((const float4*)x)[(size_t)(b*512 + t)*128 + dq];
  _Float16* o = xh + (size_t)idx*4;
  o[0]=(_Float16)v.x; o[1]=(_Float16)v.y; o[2]=(_Float16)v.z; o[3]=(_Float16)v.w;
}

// ---------------- Zx0 = x @ Wx0 + b0 ---------------------------------------
__global__ __launch_bounds__(64) void zx0_gemm(const _Float16* __restrict__ xh,
                                               const _Float16* __restrict__ wx0a,
                                               const float* __restrict__ b0,
                                               _Float16* __restrict__ zx0){
  int t   = blockIdx.x;        // 512
  int wgg = blockIdx.y;        // 64 (covers 4 wg slices)
  int l = threadIdx.x, q = l>>4, c = l&15;
  floatx4 acc[2][4];
  #pragma unroll
  for (int g=0; g<4; ++g){
    int wg = wgg*4+g;
    float bv = b0[(c>>2)*1024 + wg*4 + (c&3)];
    acc[0][g] = (floatx4){bv,bv,bv,bv};
    acc[1][g] = (floatx4){bv,bv,bv,bv};
  }
  #pragma unroll 4
  for (int ks=0; ks<16; ++ks){
    int kc = ks*4 + q;
    half8 a0 = *(const half8*)(xh + (t*32      + c)*512 + kc*8);
    half8 a1 = *(const half8*)(xh + (t*32 + 16 + c)*512 + kc*8);
    #pragma unroll
    for (int g=0; g<4; ++g){
      int wg = wgg*4+g;
      half8 b = *(const half8*)(wx0a + ((size_t)(wg*64 + kc)*16 + c)*8);
      acc[0][g] = __builtin_amdgcn_mfma_f32_16x16x32_f16(a0,b,acc[0][g],0,0,0);
      acc[1][g] = __builtin_amdgcn_mfma_f32_16x16x32_f16(a1,b,acc[1][g],0,0,0);
    }
  }
  #pragma unroll
  for (int g=0; g<4; ++g){
    int wg = wgg*4+g;
    #pragma unroll
    for (int mt=0; mt<2; ++mt)
      #pragma unroll
      for (int r=0;r<4;++r){
        int m = mt*16 + q*4 + r;
        zx0[((size_t)(t*256 + wg)*32 + m)*16 + c] = (_Float16)acc[mt][g][r];
      }
  }
}

// ---------------- persistent recurrent kernel ------------------------------
// LDS: w0 (Wh0), w1 (Wx1), w2 (Wh1): [128 kc][16 c][8] each = 96 KiB total
// A-frag for ks: lane reads h[row][ks*32 + q*8 .. +8) directly from global.
#define AF(base, ks) (*(const half8*)((base) + (ks)*32))
#define BF(w, ks)    (*(const half8*)((w) + (((ks)*4 + q)*16 + c)*8))

__global__ __launch_bounds__(128, 1) void lstm_persist(
    const _Float16* __restrict__ wrec, const _Float16* __restrict__ zx0,
    const float* __restrict__ b1g, _Float16* __restrict__ h0b,
    _Float16* __restrict__ h1a, unsigned int* __restrict__ flags)
{
  extern __shared__ _Float16 lds[];
  _Float16* w0  = lds;            // 16384 halves
  _Float16* w1  = lds + 16384;
  _Float16* w2  = lds + 32768;

  const int wg = blockIdx.x, tid = threadIdx.x;
  const int wv = tid>>6, l = tid&63, q = l>>4, c = l&15;
  const int g = (c>>2);           // gate of own column
  const int mt = wv;              // wave0 rows 0-15, wave1 rows 16-31
  const int row = mt*16 + c;      // A-frag row this lane loads

  unsigned int* gcnt  = flags + (wg>>3)*32;   // 32 groups of 8, 128B apart
  unsigned int* gdone = flags + 1024;         // 32 words (1-2 lines)

  { // stage this WG's weight slice: 98304 B = 6144 uint4
    const uint4* src = (const uint4*)(wrec + (size_t)wg*49152);
    uint4* dst = (uint4*)lds;
    for (int i=tid; i<6144; i+=128) dst[i] = src[i];
  }
  float c0[4] = {0,0,0,0}, c1[4] = {0,0,0,0};
  const float b1v = b1g[g*1024 + wg*4 + (c&3)];
  __syncthreads();

  for (int t=0; t<512; ++t){
    // ---------- phase A: z0 = Zx0[t] + h0(t-1)@Wh0 ; h0(t) ----------
    {
      const _Float16* zsrc = zx0 + ((size_t)(t*256 + wg)*32 + mt*16 + q*4)*16 + c;
      float z0v=(float)zsrc[0], z1v=(float)zsrc[16], z2v=(float)zsrc[32], z3v=(float)zsrc[48];
      floatx4 a0={0,0,0,0}, a1={0,0,0,0}, a2={0,0,0,0}, a3={0,0,0,0};
      if (t > 0){
        const _Float16* hb = h0b + (size_t)((t-1)&1)*32768 + row*1024 + q*8;
        #pragma unroll
        for (int s=0; s<8; ++s){
          a0 = __builtin_amdgcn_mfma_f32_16x16x32_f16(AF(hb,s),    BF(w0,s),    a0,0,0,0);
          a1 = __builtin_amdgcn_mfma_f32_16x16x32_f16(AF(hb,8+s),  BF(w0,8+s),  a1,0,0,0);
          a2 = __builtin_amdgcn_mfma_f32_16x16x32_f16(AF(hb,16+s), BF(w0,16+s), a2,0,0,0);
          a3 = __builtin_amdgcn_mfma_f32_16x16x32_f16(AF(hb,24+s), BF(w0,24+s), a3,0,0,0);
        }
      }
      floatx4 acc = (a0+a1)+(a2+a3);
      acc[0]+=z0v; acc[1]+=z1v; acc[2]+=z2v; acc[3]+=z3v;
      _Float16* h0d = h0b + (size_t)(t&1)*32768;
      #pragma unroll
      for (int r=0;r<4;++r){
        float v0 = acc[r];
        float v1 = __shfl_xor(v0, 4, 64);
        float v2 = __shfl_xor(v0, 8, 64);
        float v3 = __shfl_xor(v1, 8, 64);
        float zi = (g==0)?v0:(g==1)?v1:(g==2)?v2:v3;
        float zf = (g==0)?v1:(g==1)?v0:(g==2)?v3:v2;
        float zg = (g==0)?v2:(g==1)?v3:(g==2)?v0:v1;
        float zo = (g==0)?v3:(g==1)?v2:(g==2)?v1:v0;
        float cn = fsig(zf)*c0[r] + fsig(zi)*ftanhf(zg);
        c0[r] = cn;
        float hv = fsig(zo)*ftanhf(cn);
        unsigned hb16 = (unsigned)__builtin_bit_cast(unsigned short, (_Float16)hv);
        unsigned up   = (unsigned)__shfl_xor((int)hb16, 1, 64);
        if (g==0 && (c&1)==0)
          __hip_atomic_store((unsigned*)(h0d + (mt*16 + q*4 + r)*1024 + wg*4 + c),
                             hb16 | (up<<16),
                             __ATOMIC_RELAXED, __HIP_MEMORY_SCOPE_AGENT);
      }
    }
    __syncthreads();   // drains each wave's vmcnt: h0(t) (and h1(t-1)) at LLC
    // ---------- device barrier: 32x8 tree, leaders store gdone ----------
    if (tid==0){
      unsigned o = __hip_atomic_fetch_add(gcnt, 1u, __ATOMIC_RELAXED,
                                          __HIP_MEMORY_SCOPE_AGENT);
      if (o == 8u*(unsigned)(t+1) - 1u)
        __hip_atomic_store(gdone + (wg>>3), (unsigned)(t+1),
                           __ATOMIC_RELAXED, __HIP_MEMORY_SCOPE_AGENT);
    }
    if (wv==0){
      unsigned tgt = (unsigned)(t+1);
      const unsigned* gd = gdone + (l&31);
      while (!__all(__hip_atomic_load(gd, __ATOMIC_RELAXED,
                                      __HIP_MEMORY_SCOPE_AGENT) >= tgt))
        __builtin_amdgcn_s_sleep(2);
    }
    __syncthreads();
    __builtin_amdgcn_fence(__ATOMIC_ACQUIRE, "agent");  // buffer_inv: drop stale L2

    // ---------- phase B: z1 = h1(t-1)@Wh1 + h0(t)@Wx1 + b1 ; h1(t) ----------
    {
      floatx4 accP={b1v,b1v,b1v,b1v}, accQ={0,0,0,0}, accR={0,0,0,0}, accS={0,0,0,0};
      if (t > 0){
        const _Float16* h1p = h1a + (size_t)(t-1)*32768 + row*1024 + q*8;
        #pragma unroll
        for (int s=0; s<16; ++s){
          accP = __builtin_amdgcn_mfma_f32_16x16x32_f16(AF(h1p,s),    BF(w2,s),    accP,0,0,0);
          accQ = __builtin_amdgcn_mfma_f32_16x16x32_f16(AF(h1p,16+s), BF(w2,16+s), accQ,0,0,0);
        }
      }
      const _Float16* h0c = h0b + (size_t)(t&1)*32768 + row*1024 + q*8;
      #pragma unroll
      for (int s=0; s<16; ++s){
        accR = __builtin_amdgcn_mfma_f32_16x16x32_f16(AF(h0c,s),    BF(w1,s),    accR,0,0,0);
        accS = __builtin_amdgcn_mfma_f32_16x16x32_f16(AF(h0c,16+s), BF(w1,16+s), accS,0,0,0);
      }
      floatx4 acc1 = (accP+accQ)+(accR+accS);
      _Float16* h1d = h1a + (size_t)t*32768;
      #pragma unroll
      for (int r=0;r<4;++r){
        float v0 = acc1[r];
        float v1 = __shfl_xor(v0, 4, 64);
        float v2 = __shfl_xor(v0, 8, 64);
        float v3 = __shfl_xor(v1, 8, 64);
        float zi = (g==0)?v0:(g==1)?v1:(g==2)?v2:v3;
        float zf = (g==0)?v1:(g==1)?v0:(g==2)?v3:v2;
        float zg = (g==0)?v2:(g==1)?v3:(g==2)?v0:v1;
        float zo = (g==0)?v3:(g==1)?v2:(g==2)?v1:v0;
        float cn = fsig(zf)*c1[r] + fsig(zi)*ftanhf(zg);
        c1[r] = cn;
        float hv = fsig(zo)*ftanhf(cn);
        unsigned hb16 = (unsigned)__builtin_bit_cast(unsigned short, (_Float16)hv);
        unsigned up   = (unsigned)__shfl_xor((int)hb16, 1, 64);
        if (g==0 && (c&1)==0)
          __hip_atomic_store((unsigned*)(h1d + (mt*16 + q*4 + r)*1024 + wg*4 + c),
                             hb16 | (up<<16),
                             __ATOMIC_RELAXED, __HIP_MEMORY_SCOPE_AGENT);
      }
    }
    // h1(t) stores drain at next iteration's __syncthreads, before arrival(t+1).
  }
}

// ---------------- Y = H1 @ Wd + bd -----------------------------------------
__global__ __launch_bounds__(256) void wd_gemm(const _Float16* __restrict__ h1a,
                                               const _Float16* __restrict__ wda,
                                               const float* __restrict__ bd,
                                               float* __restrict__ y){
  int mb = blockIdx.x;   // 512 blocks of 32 rows (rows = t*32+b)
  int nb = blockIdx.y;   // 4 blocks of 128 cols
  int tid = threadIdx.x, wv = tid>>6, l = tid&63, q = l>>4, c = l&15;
  int mt = wv & 1, nh = wv >> 1;
  floatx4 acc[4];
  #pragma unroll
  for (int gg=0; gg<4; ++gg) acc[gg] = (floatx4){0.f,0.f,0.f,0.f};
  const _Float16* arow = h1a + (size_t)(mb*32 + mt*16 + c)*1024;
  #pragma unroll 4
  for (int ks=0; ks<32; ++ks){
    int kc = ks*4 + q;
    half8 a = *(const half8*)(arow + kc*8);
    #pragma unroll
    for (int gg=0; gg<4; ++gg){
      int nt = nb*8 + nh*4 + gg;
      half8 b = *(const half8*)(wda + ((size_t)(nt*128 + kc)*16 + c)*8);
      acc[gg] = __builtin_amdgcn_mfma_f32_16x16x32_f16(a,b,acc[gg],0,0,0);
    }
  }
  #pragma unroll
  for (int gg=0; gg<4; ++gg){
    int o = nb*128 + nh*64 + gg*16 + c;
    float bdv = bd[o];
    #pragma unroll
    for (int r=0;r<4;++r){
      int row = mb*32 + mt*16 + q*4 + r;
      int tt = row >> 5, bb = row & 31;
      y[(size_t)bb*262144 + tt*512 + o] = acc[gg][r] + bdv;
    }
  }
}

// ---------------------------------------------------------------------------
extern "C" void kernel_launch(void* const* d_in, const int* in_sizes, int n_in,
                              void* d_out, int out_size, void* d_ws, size_t ws_size,
                              hipStream_t stream){
  const float* x   = (const float*)d_in[0];
  const float* Wx0 = (const float*)d_in[1];
  const float* Wh0 = (const float*)d_in[2];
  const float* b0  = (const float*)d_in[3];
  const float* Wx1 = (const float*)d_in[4];
  const float* Wh1 = (const float*)d_in[5];
  const float* b1  = (const float*)d_in[6];
  const float* Wd  = (const float*)d_in[7];
  const float* bd  = (const float*)d_in[8];
  float* y = (float*)d_out;
  char* ws = (char*)d_ws;

  _Float16* wrec = (_Float16*)(ws + WREC_OFF);
  _Float16* wx0a = (_Float16*)(ws + WX0_OFF);
  _Float16* wda  = (_Float16*)(ws + WD_OFF);
  _Float16* xh   = (_Float16*)(ws + XH_OFF);
  _Float16* zx0  = (_Float16*)(ws + ZX0_OFF);
  _Float16* h0b  = (_Float16*)(ws + H0_OFF);
  _Float16* h1a  = (_Float16*)(ws + H1_OFF);
  unsigned int* flags = (unsigned int*)(ws + FLAGS_OFF);

  hipMemsetAsync(flags, 0, 8192, stream);
  conv_wrec<<<dim3(6144), dim3(256), 0, stream>>>(Wh0, Wx1, Wh1, wrec);
  conv_wx0 <<<dim3(1024), dim3(256), 0, stream>>>(Wx0, wx0a);
  conv_wd  <<<dim3(256),  dim3(256), 0, stream>>>(Wd, wda);
  conv_x   <<<dim3(8192), dim3(256), 0, stream>>>(x, xh);
  zx0_gemm <<<dim3(512,64), dim3(64), 0, stream>>>(xh, wx0a, b0, zx0);
  hipFuncSetAttribute((const void*)lstm_persist,
                      hipFuncAttributeMaxDynamicSharedMemorySize, 98304);
  lstm_persist<<<dim3(256), dim3(128), 98304, stream>>>(wrec, zx0, b1, h0b, h1a, flags);
  wd_gemm  <<<dim3(512,4), dim3(256), 0, stream>>>(h1a, wda, bd, y);
}

// Round 6
// 8052.864 us; speedup vs baseline: 2.8789x; 1.0749x over previous
//
#include <hip/hip_runtime.h>

// ---------------------------------------------------------------------------
// SimpleLSTM: 2-layer LSTM (B=32,T=512,D=512,H=1024) + output proj (O=512).
//   conv kernels : fp32 -> f16, weights rearranged into MFMA B-frag order
//   zx0_gemm     : Zx0[t][wg][m][c] = x@Wx0 + b0  (parallel over all T)
//   lstm_persist : 256 persistent WGs (1/CU), recurrent weights in LDS
//   wd_gemm      : Y = H1 @ Wd + bd
// R4: tree barrier, 1 barrier/step (22.7 -> 14.5 ms).
// R5: uncached h-exchange (no release wbl2), direct-from-global A-frags,
//     block 128 (14.5 -> 8.3 ms).
// R6: barrier poll de-congestion: single-lane polls on per-group go-lines
//     (8 pollers x 1 dword per line, was 256 WGs x 64-lane gathers on 2
//     lines); root completer broadcast-stores 32 go-words. Merged phase:
//     B(t) and A(t+1) computed between barriers, h0(t) fragments loaded
//     once for both Wh0/Wx1 chains; zx0 prefetched pre-poll.
// ---------------------------------------------------------------------------

typedef _Float16 half8  __attribute__((ext_vector_type(8)));
typedef float    floatx4 __attribute__((ext_vector_type(4)));

// ws layout (bytes)
#define WREC_OFF   0UL            // [256 wg][3 mat][128 kc][16 c][8] f16 = 24 MiB
#define WX0_OFF    25165824UL     // [256 wg][64 kc][16 c][8] f16        = 4 MiB
#define WD_OFF     29360128UL     // [32 nt][128 kc][16 c][8] f16        = 1 MiB
#define XH_OFF     30408704UL     // [512 t][32 b][512 d] f16            = 16 MiB
#define ZX0_OFF    47185920UL     // [512 t][256 wg][32 m][16 c] f16     = 128 MiB
#define H0_OFF     181403648UL    // [2][32][1024] f16 (double-buffered)
#define H1_OFF     181534720UL    // [512 t][32 m][1024 k] f16           = 32 MiB
#define FLAGS_OFF  215089152UL    // 24 KiB: gcnt[32]@256B, root, go[32]@256B

__device__ __forceinline__ float fsig(float x){ return 1.0f/(1.0f + __expf(-x)); }
__device__ __forceinline__ float ftanhf(float x){
  float e = __expf(2.0f*fabsf(x));
  float r = 1.0f - 2.0f/(e + 1.0f);
  return copysignf(r, x);
}

// ---------------- weight conversion ----------------------------------------
__global__ void conv_wrec(const float* __restrict__ Wh0,
                          const float* __restrict__ Wx1,
                          const float* __restrict__ Wh1,
                          _Float16* __restrict__ out){
  int idx = blockIdx.x*256 + threadIdx.x;          // ((wg*3+mat)*128+kc)*16+c
  if (idx >= 256*3*128*16) return;
  int c  = idx & 15;
  int t1 = idx >> 4;
  int kc = t1 & 127;
  int t2 = t1 >> 7;
  int mat = t2 % 3;
  int wg  = t2 / 3;
  const float* W = (mat==0) ? Wh0 : (mat==1) ? Wx1 : Wh1;
  int col = (c>>2)*1024 + wg*4 + (c&3);
  _Float16* o = out + (size_t)idx*8;
  #pragma unroll
  for (int j=0;j<8;++j) o[j] = (_Float16)W[(kc*8+j)*4096 + col];
}

__global__ void conv_wx0(const float* __restrict__ W, _Float16* __restrict__ out){
  int idx = blockIdx.x*256 + threadIdx.x;          // ((wg*64+kc)*16+c)
  if (idx >= 256*64*16) return;
  int c  = idx & 15;
  int kc = (idx >> 4) & 63;
  int wg = idx >> 10;
  int col = (c>>2)*1024 + wg*4 + (c&3);
  _Float16* o = out + (size_t)idx*8;
  #pragma unroll
  for (int j=0;j<8;++j) o[j] = (_Float16)W[(kc*8+j)*4096 + col];
}

__global__ void conv_wd(const float* __restrict__ W, _Float16* __restrict__ out){
  int idx = blockIdx.x*256 + threadIdx.x;          // ((nt*128+kc)*16+c)
  if (idx >= 32*128*16) return;
  int c  = idx & 15;
  int kc = (idx >> 4) & 127;
  int nt = idx >> 11;
  int col = nt*16 + c;
  _Float16* o = out + (size_t)idx*8;
  #pragma unroll
  for (int j=0;j<8;++j) o[j] = (_Float16)W[(kc*8+j)*512 + col];
}

// x[b][t][d] fp32 -> xh[t*32+b][d] f16  (time-major rows for zx0_gemm)
__global__ void conv_x(const float* __restrict__ x, _Float16* __restrict__ xh){
  int idx = blockIdx.x*256 + threadIdx.x;          // [bt][dq], dq = d/4
  if (idx >= 2097152) return;
  int dq = idx & 127;
  int bt = idx >> 7;          // t*32 + b
  int b  = bt & 31;
  int t  = bt >> 5;
  float4 v = ((const float4*)x)[(size_t)(b*512 + t)*128 + dq];
  _Float16* o = xh + (size_t)idx*4;
  o[0]=(_Float16)v.x; o[1]=(_Float16)v.y; o[2]=(_Float16)v.z; o[3]=(_Float16)v.w;
}

// ---------------- Zx0 = x @ Wx0 + b0 ---------------------------------------
__global__ __launch_bounds__(64) void zx0_gemm(const _Float16* __restrict__ xh,
                                               const _Float16* __restrict__ wx0a,
                                               const float* __restrict__ b0,
                                               _Float16* __restrict__ zx0){
  int t   = blockIdx.x;        // 512
  int wgg = blockIdx.y;        // 64 (covers 4 wg slices)
  int l = threadIdx.x, q = l>>4, c = l&15;
  floatx4 acc[2][4];
  #pragma unroll
  for (int g=0; g<4; ++g){
    int wg = wgg*4+g;
    float bv = b0[(c>>2)*1024 + wg*4 + (c&3)];
    acc[0][g] = (floatx4){bv,bv,bv,bv};
    acc[1][g] = (floatx4){bv,bv,bv,bv};
  }
  #pragma unroll 4
  for (int ks=0; ks<16; ++ks){
    int kc = ks*4 + q;
    half8 a0 = *(const half8*)(xh + (t*32      + c)*512 + kc*8);
    half8 a1 = *(const half8*)(xh + (t*32 + 16 + c)*512 + kc*8);
    #pragma unroll
    for (int g=0; g<4; ++g){
      int wg = wgg*4+g;
      half8 b = *(const half8*)(wx0a + ((size_t)(wg*64 + kc)*16 + c)*8);
      acc[0][g] = __builtin_amdgcn_mfma_f32_16x16x32_f16(a0,b,acc[0][g],0,0,0);
      acc[1][g] = __builtin_amdgcn_mfma_f32_16x16x32_f16(a1,b,acc[1][g],0,0,0);
    }
  }
  #pragma unroll
  for (int g=0; g<4; ++g){
    int wg = wgg*4+g;
    #pragma unroll
    for (int mt=0; mt<2; ++mt)
      #pragma unroll
      for (int r=0;r<4;++r){
        int m = mt*16 + q*4 + r;
        zx0[((size_t)(t*256 + wg)*32 + m)*16 + c] = (_Float16)acc[mt][g][r];
      }
  }
}

// ---------------- persistent recurrent kernel ------------------------------
// LDS: w0 (Wh0), w1 (Wx1), w2 (Wh1): [128 kc][16 c][8] each = 96 KiB total
#define AF(base, ks) (*(const half8*)((base) + (ks)*32))
#define BF(w, ks)    (*(const half8*)((w) + (((ks)*4 + q)*16 + c)*8))

// gate exchange + cell update + packed agent-scope store of h (cols wg*4..+3)
__device__ __forceinline__ void gates_store(floatx4 acc, float* cs,
    _Float16* dst, int g, int c, int mt, int q, int wg){
  #pragma unroll
  for (int r=0;r<4;++r){
    float v0 = acc[r];
    float v1 = __shfl_xor(v0, 4, 64);
    float v2 = __shfl_xor(v0, 8, 64);
    float v3 = __shfl_xor(v1, 8, 64);
    float zi = (g==0)?v0:(g==1)?v1:(g==2)?v2:v3;
    float zf = (g==0)?v1:(g==1)?v0:(g==2)?v3:v2;
    float zg = (g==0)?v2:(g==1)?v3:(g==2)?v0:v1;
    float zo = (g==0)?v3:(g==1)?v2:(g==2)?v1:v0;
    float cn = fsig(zf)*cs[r] + fsig(zi)*ftanhf(zg);
    cs[r] = cn;
    float hv = fsig(zo)*ftanhf(cn);
    unsigned hb16 = (unsigned)__builtin_bit_cast(unsigned short, (_Float16)hv);
    unsigned up   = (unsigned)__shfl_xor((int)hb16, 1, 64);
    if (g==0 && (c&1)==0)
      __hip_atomic_store((unsigned*)(dst + (mt*16 + q*4 + r)*1024 + wg*4 + c),
                         hb16 | (up<<16),
                         __ATOMIC_RELAXED, __HIP_MEMORY_SCOPE_AGENT);
  }
}

__global__ __launch_bounds__(128, 1) void lstm_persist(
    const _Float16* __restrict__ wrec, const _Float16* __restrict__ zx0,
    const float* __restrict__ b1g, _Float16* __restrict__ h0b,
    _Float16* __restrict__ h1a, unsigned int* __restrict__ flags)
{
  extern __shared__ _Float16 lds[];
  _Float16* w0  = lds;            // 16384 halves
  _Float16* w1  = lds + 16384;
  _Float16* w2  = lds + 32768;

  const int wg = blockIdx.x, tid = threadIdx.x;
  const int wv = tid>>6, l = tid&63, q = l>>4, c = l&15;
  const int g = (c>>2);           // gate of own column
  const int mt = wv;              // wave0 rows 0-15, wave1 rows 16-31
  const int row = mt*16 + c;      // A-frag row this lane loads
  const int grp = wg >> 3;        // 32 groups of 8

  unsigned int* gcnt = flags + grp*64;        // 256B apart
  unsigned int* root = flags + 2048;          // own line
  unsigned int* go   = flags + 4096;          // go[g2] at 4096 + g2*64

  { // stage this WG's weight slice: 98304 B = 6144 uint4
    const uint4* src = (const uint4*)(wrec + (size_t)wg*49152);
    uint4* dst = (uint4*)lds;
    for (int i=tid; i<6144; i+=128) dst[i] = src[i];
  }
  float c0[4] = {0,0,0,0}, c1[4] = {0,0,0,0};
  const float b1v = b1g[g*1024 + wg*4 + (c&3)];
  __syncthreads();

  // ---------- prologue: A(0): h0(0) = act(Zx0[0]) (h0(-1)=0) ----------
  {
    const _Float16* zsrc = zx0 + ((size_t)wg*32 + mt*16 + q*4)*16 + c;
    floatx4 a;
    a[0]=(float)zsrc[0]; a[1]=(float)zsrc[16]; a[2]=(float)zsrc[32]; a[3]=(float)zsrc[48];
    gates_store(a, c0, h0b, g, c, mt, q, wg);   // parity 0
  }

  for (int t=0; t<512; ++t){
    // prefetch zx0 for A(t+1) (register-resident across the barrier)
    int tn = (t<511) ? t+1 : 511;
    const _Float16* zsrc = zx0 + ((size_t)(tn*256 + wg)*32 + mt*16 + q*4)*16 + c;
    float pz0=(float)zsrc[0], pz1=(float)zsrc[16], pz2=(float)zsrc[32], pz3=(float)zsrc[48];

    __syncthreads();   // drains vmcnt: h0(t)/h1(t-1) stores visible at LLC
    // ---------- device barrier: 32x8 tree + 32-line go broadcast ----------
    if (tid==0){
      unsigned tgt = (unsigned)(t+1);
      unsigned o = __hip_atomic_fetch_add(gcnt, 1u, __ATOMIC_RELAXED,
                                          __HIP_MEMORY_SCOPE_AGENT);
      if (o == 8u*tgt - 1u){
        unsigned r = __hip_atomic_fetch_add(root, 1u, __ATOMIC_RELAXED,
                                            __HIP_MEMORY_SCOPE_AGENT);
        if (r == 32u*tgt - 1u){
          #pragma unroll
          for (int g2=0; g2<32; ++g2)
            __hip_atomic_store(go + g2*64, tgt, __ATOMIC_RELAXED,
                               __HIP_MEMORY_SCOPE_AGENT);
        }
      }
      while (__hip_atomic_load(go + grp*64, __ATOMIC_RELAXED,
                               __HIP_MEMORY_SCOPE_AGENT) < tgt)
        __builtin_amdgcn_s_sleep(1);
    }
    __syncthreads();
    __builtin_amdgcn_fence(__ATOMIC_ACQUIRE, "agent");  // drop stale L2

    // ---------- merged compute: B(t) and A(t+1) ----------
    const _Float16* h0c = h0b + (size_t)(t&1)*32768 + row*1024 + q*8;
    floatx4 aA0={0,0,0,0}, aA1={0,0,0,0};
    floatx4 aB0={b1v,b1v,b1v,b1v}, aB1={0,0,0,0};
    floatx4 aC0={0,0,0,0}, aC1={0,0,0,0};
    if (t > 0){
      const _Float16* h1p = h1a + (size_t)(t-1)*32768 + row*1024 + q*8;
      #pragma unroll
      for (int s=0; s<16; ++s){
        aC0 = __builtin_amdgcn_mfma_f32_16x16x32_f16(AF(h1p,s),    BF(w2,s),    aC0,0,0,0);
        aC1 = __builtin_amdgcn_mfma_f32_16x16x32_f16(AF(h1p,16+s), BF(w2,16+s), aC1,0,0,0);
      }
    }
    #pragma unroll
    for (int s=0; s<16; ++s){
      half8 f0 = AF(h0c,s), f1 = AF(h0c,16+s);
      aB0 = __builtin_amdgcn_mfma_f32_16x16x32_f16(f0, BF(w1,s),    aB0,0,0,0);
      aB1 = __builtin_amdgcn_mfma_f32_16x16x32_f16(f1, BF(w1,16+s), aB1,0,0,0);
      aA0 = __builtin_amdgcn_mfma_f32_16x16x32_f16(f0, BF(w0,s),    aA0,0,0,0);
      aA1 = __builtin_amdgcn_mfma_f32_16x16x32_f16(f1, BF(w0,16+s), aA1,0,0,0);
    }
    // B(t): h1(t)
    {
      floatx4 z1 = (aB0+aB1)+(aC0+aC1);
      gates_store(z1, c1, h1a + (size_t)t*32768, g, c, mt, q, wg);
    }
    // A(t+1): h0(t+1)
    if (t < 511){
      floatx4 z0 = aA0+aA1;
      z0[0]+=pz0; z0[1]+=pz1; z0[2]+=pz2; z0[3]+=pz3;
      gates_store(z0, c0, h0b + (size_t)((t+1)&1)*32768, g, c, mt, q, wg);
    }
  }
}

// ---------------- Y = H1 @ Wd + bd -----------------------------------------
__global__ __launch_bounds__(256) void wd_gemm(const _Float16* __restrict__ h1a,
                                               const _Float16* __restrict__ wda,
                                               const float* __restrict__ bd,
                                               float* __restrict__ y){
  int mb = blockIdx.x;   // 512 blocks of 32 rows (rows = t*32+b)
  int nb = blockIdx.y;   // 4 blocks of 128 cols
  int tid = threadIdx.x, wv = tid>>6, l = tid&63, q = l>>4, c = l&15;
  int mt = wv & 1, nh = wv >> 1;
  floatx4 acc[4];
  #pragma unroll
  for (int gg=0; gg<4; ++gg) acc[gg] = (floatx4){0.f,0.f,0.f,0.f};
  const _Float16* arow = h1a + (size_t)(mb*32 + mt*16 + c)*1024;
  #pragma unroll 4
  for (int ks=0; ks<32; ++ks){
    int kc = ks*4 + q;
    half8 a = *(const half8*)(arow + kc*8);
    #pragma unroll
    for (int gg=0; gg<4; ++gg){
      int nt = nb*8 + nh*4 + gg;
      half8 b = *(const half8*)(wda + ((size_t)(nt*128 + kc)*16 + c)*8);
      acc[gg] = __builtin_amdgcn_mfma_f32_16x16x32_f16(a,b,acc[gg],0,0,0);
    }
  }
  #pragma unroll
  for (int gg=0; gg<4; ++gg){
    int o = nb*128 + nh*64 + gg*16 + c;
    float bdv = bd[o];
    #pragma unroll
    for (int r=0;r<4;++r){
      int row = mb*32 + mt*16 + q*4 + r;
      int tt = row >> 5, bb = row & 31;
      y[(size_t)bb*262144 + tt*512 + o] = acc[gg][r] + bdv;
    }
  }
}

// ---------------------------------------------------------------------------
extern "C" void kernel_launch(void* const* d_in, const int* in_sizes, int n_in,
                              void* d_out, int out_size, void* d_ws, size_t ws_size,
                              hipStream_t stream){
  const float* x   = (const float*)d_in[0];
  const float* Wx0 = (const float*)d_in[1];
  const float* Wh0 = (const float*)d_in[2];
  const float* b0  = (const float*)d_in[3];
  const float* Wx1 = (const float*)d_in[4];
  const float* Wh1 = (const float*)d_in[5];
  const float* b1  = (const float*)d_in[6];
  const float* Wd  = (const float*)d_in[7];
  const float* bd  = (const float*)d_in[8];
  float* y = (float*)d_out;
  char* ws = (char*)d_ws;

  _Float16* wrec = (_Float16*)(ws + WREC_OFF);
  _Float16* wx0a = (_Float16*)(ws + WX0_OFF);
  _Float16* wda  = (_Float16*)(ws + WD_OFF);
  _Float16* xh   = (_Float16*)(ws + XH_OFF);
  _Float16* zx0  = (_Float16*)(ws + ZX0_OFF);
  _Float16* h0b  = (_Float16*)(ws + H0_OFF);
  _Float16* h1a  = (_Float16*)(ws + H1_OFF);
  unsigned int* flags = (unsigned int*)(ws + FLAGS_OFF);

  hipMemsetAsync(flags, 0, 24576, stream);
  conv_wrec<<<dim3(6144), dim3(256), 0, stream>>>(Wh0, Wx1, Wh1, wrec);
  conv_wx0 <<<dim3(1024), dim3(256), 0, stream>>>(Wx0, wx0a);
  conv_wd  <<<dim3(256),  dim3(256), 0, stream>>>(Wd, wda);
  conv_x   <<<dim3(8192), dim3(256), 0, stream>>>(x, xh);
  zx0_gemm <<<dim3(512,64), dim3(64), 0, stream>>>(xh, wx0a, b0, zx0);
  hipFuncSetAttribute((const void*)lstm_persist,
                      hipFuncAttributeMaxDynamicSharedMemorySize, 98304);
  lstm_persist<<<dim3(256), dim3(128), 98304, stream>>>(wrec, zx0, b1, h0b, h1a, flags);
  wd_gemm  <<<dim3(512,4), dim3(256), 0, stream>>>(h1a, wda, bd, y);
}

// Round 7
// 6647.804 us; speedup vs baseline: 3.4874x; 1.2114x over previous
//
#include <hip/hip_runtime.h>

// ---------------------------------------------------------------------------
// SimpleLSTM: 2-layer LSTM (B=32,T=512,D=512,H=1024) + output proj (O=512).
//   conv kernels : fp32 -> f16, weights rearranged into MFMA B-frag order
//   zx0_gemm     : Zx0[t][wg][m][c] = x@Wx0 + b0  (parallel over all T)
//   lstm_persist : 256 persistent WGs (1/CU), recurrent weights in LDS
//   wd_gemm      : Y = H1 @ Wd + bd
// R4: tree barrier, 1 barrier/step (22.7 -> 14.5 ms).
// R5: uncached h-exchange stores, direct-from-global A-frags (14.5 -> 8.3).
// R6: poll de-congestion + merged B(t)/A(t+1) phase (8.3 -> 7.6).
// R7: NO FENCES. The agent acquire (buffer_inv, full per-XCD L2 flash-inv
//     every step on all CUs) is deleted. h1a is t-indexed: consumers read
//     lines no XCD ever cached (producers store uncached to LLC) -> cached
//     reads are fresh by construction. h0b recycles every 2 steps, so its
//     reads switch to uncached agent-scope atomic b64 loads (LLC-direct).
//     zx0/weights stay cached/LDS and now remain L2-warm across steps.
// ---------------------------------------------------------------------------

typedef _Float16 half8  __attribute__((ext_vector_type(8)));
typedef float    floatx4 __attribute__((ext_vector_type(4)));

// ws layout (bytes)
#define WREC_OFF   0UL            // [256 wg][3 mat][128 kc][16 c][8] f16 = 24 MiB
#define WX0_OFF    25165824UL     // [256 wg][64 kc][16 c][8] f16        = 4 MiB
#define WD_OFF     29360128UL     // [32 nt][128 kc][16 c][8] f16        = 1 MiB
#define XH_OFF     30408704UL     // [512 t][32 b][512 d] f16            = 16 MiB
#define ZX0_OFF    47185920UL     // [512 t][256 wg][32 m][16 c] f16     = 128 MiB
#define H0_OFF     181403648UL    // [2][32][1024] f16 (double-buffered)
#define H1_OFF     181534720UL    // [512 t][32 m][1024 k] f16           = 32 MiB
#define FLAGS_OFF  215089152UL    // 24 KiB: gcnt[32]@256B, root, go[32]@256B

__device__ __forceinline__ float fsig(float x){ return 1.0f/(1.0f + __expf(-x)); }
__device__ __forceinline__ float ftanhf(float x){
  float e = __expf(2.0f*fabsf(x));
  float r = 1.0f - 2.0f/(e + 1.0f);
  return copysignf(r, x);
}

// ---------------- weight conversion ----------------------------------------
__global__ void conv_wrec(const float* __restrict__ Wh0,
                          const float* __restrict__ Wx1,
                          const float* __restrict__ Wh1,
                          _Float16* __restrict__ out){
  int idx = blockIdx.x*256 + threadIdx.x;          // ((wg*3+mat)*128+kc)*16+c
  if (idx >= 256*3*128*16) return;
  int c  = idx & 15;
  int t1 = idx >> 4;
  int kc = t1 & 127;
  int t2 = t1 >> 7;
  int mat = t2 % 3;
  int wg  = t2 / 3;
  const float* W = (mat==0) ? Wh0 : (mat==1) ? Wx1 : Wh1;
  int col = (c>>2)*1024 + wg*4 + (c&3);
  _Float16* o = out + (size_t)idx*8;
  #pragma unroll
  for (int j=0;j<8;++j) o[j] = (_Float16)W[(kc*8+j)*4096 + col];
}

__global__ void conv_wx0(const float* __restrict__ W, _Float16* __restrict__ out){
  int idx = blockIdx.x*256 + threadIdx.x;          // ((wg*64+kc)*16+c)
  if (idx >= 256*64*16) return;
  int c  = idx & 15;
  int kc = (idx >> 4) & 63;
  int wg = idx >> 10;
  int col = (c>>2)*1024 + wg*4 + (c&3);
  _Float16* o = out + (size_t)idx*8;
  #pragma unroll
  for (int j=0;j<8;++j) o[j] = (_Float16)W[(kc*8+j)*4096 + col];
}

__global__ void conv_wd(const float* __restrict__ W, _Float16* __restrict__ out){
  int idx = blockIdx.x*256 + threadIdx.x;          // ((nt*128+kc)*16+c)
  if (idx >= 32*128*16) return;
  int c  = idx & 15;
  int kc = (idx >> 4) & 127;
  int nt = idx >> 11;
  int col = nt*16 + c;
  _Float16* o = out + (size_t)idx*8;
  #pragma unroll
  for (int j=0;j<8;++j) o[j] = (_Float16)W[(kc*8+j)*512 + col];
}

// x[b][t][d] fp32 -> xh[t*32+b][d] f16  (time-major rows for zx0_gemm)
__global__ void conv_x(const float* __restrict__ x, _Float16* __restrict__ xh){
  int idx = blockIdx.x*256 + threadIdx.x;          // [bt][dq], dq = d/4
  if (idx >= 2097152) return;
  int dq = idx & 127;
  int bt = idx >> 7;          // t*32 + b
  int b  = bt & 31;
  int t  = bt >> 5;
  float4 v = ((const float4*)x)[(size_t)(b*512 + t)*128 + dq];
  _Float16* o = xh + (size_t)idx*4;
  o[0]=(_Float16)v.x; o[1]=(_Float16)v.y; o[2]=(_Float16)v.z; o[3]=(_Float16)v.w;
}

// ---------------- Zx0 = x @ Wx0 + b0 ---------------------------------------
__global__ __launch_bounds__(64) void zx0_gemm(const _Float16* __restrict__ xh,
                                               const _Float16* __restrict__ wx0a,
                                               const float* __restrict__ b0,
                                               _Float16* __restrict__ zx0){
  int t   = blockIdx.x;        // 512
  int wgg = blockIdx.y;        // 64 (covers 4 wg slices)
  int l = threadIdx.x, q = l>>4, c = l&15;
  floatx4 acc[2][4];
  #pragma unroll
  for (int g=0; g<4; ++g){
    int wg = wgg*4+g;
    float bv = b0[(c>>2)*1024 + wg*4 + (c&3)];
    acc[0][g] = (floatx4){bv,bv,bv,bv};
    acc[1][g] = (floatx4){bv,bv,bv,bv};
  }
  #pragma unroll 4
  for (int ks=0; ks<16; ++ks){
    int kc = ks*4 + q;
    half8 a0 = *(const half8*)(xh + (t*32      + c)*512 + kc*8);
    half8 a1 = *(const half8*)(xh + (t*32 + 16 + c)*512 + kc*8);
    #pragma unroll
    for (int g=0; g<4; ++g){
      int wg = wgg*4+g;
      half8 b = *(const half8*)(wx0a + ((size_t)(wg*64 + kc)*16 + c)*8);
      acc[0][g] = __builtin_amdgcn_mfma_f32_16x16x32_f16(a0,b,acc[0][g],0,0,0);
      acc[1][g] = __builtin_amdgcn_mfma_f32_16x16x32_f16(a1,b,acc[1][g],0,0,0);
    }
  }
  #pragma unroll
  for (int g=0; g<4; ++g){
    int wg = wgg*4+g;
    #pragma unroll
    for (int mt=0; mt<2; ++mt)
      #pragma unroll
      for (int r=0;r<4;++r){
        int m = mt*16 + q*4 + r;
        zx0[((size_t)(t*256 + wg)*32 + m)*16 + c] = (_Float16)acc[mt][g][r];
      }
  }
}

// ---------------- persistent recurrent kernel ------------------------------
// LDS: w0 (Wh0), w1 (Wx1), w2 (Wh1): [128 kc][16 c][8] each = 96 KiB total
#define AF(base, ks)  (*(const half8*)((base) + (ks)*32))
#define BF(w, ks)     (*(const half8*)((w) + (((ks)*4 + q)*16 + c)*8))

// uncached (LLC-direct) 16B load as 2x b64 agent atomics — for recycled h0b
__device__ __forceinline__ half8 ldu128(const _Float16* p){
  const unsigned long long* u = (const unsigned long long*)p;
  unsigned long long lo = __hip_atomic_load(u,   __ATOMIC_RELAXED, __HIP_MEMORY_SCOPE_AGENT);
  unsigned long long hi = __hip_atomic_load(u+1, __ATOMIC_RELAXED, __HIP_MEMORY_SCOPE_AGENT);
  union { unsigned long long w[2]; half8 h; } v;
  v.w[0]=lo; v.w[1]=hi;
  return v.h;
}
#define AFU(base, ks) ldu128((base) + (ks)*32)

// gate exchange + cell update + packed agent-scope store of h (cols wg*4..+3)
__device__ __forceinline__ void gates_store(floatx4 acc, float* cs,
    _Float16* dst, int g, int c, int mt, int q, int wg){
  #pragma unroll
  for (int r=0;r<4;++r){
    float v0 = acc[r];
    float v1 = __shfl_xor(v0, 4, 64);
    float v2 = __shfl_xor(v0, 8, 64);
    float v3 = __shfl_xor(v1, 8, 64);
    float zi = (g==0)?v0:(g==1)?v1:(g==2)?v2:v3;
    float zf = (g==0)?v1:(g==1)?v0:(g==2)?v3:v2;
    float zg = (g==0)?v2:(g==1)?v3:(g==2)?v0:v1;
    float zo = (g==0)?v3:(g==1)?v2:(g==2)?v1:v0;
    float cn = fsig(zf)*cs[r] + fsig(zi)*ftanhf(zg);
    cs[r] = cn;
    float hv = fsig(zo)*ftanhf(cn);
    unsigned hb16 = (unsigned)__builtin_bit_cast(unsigned short, (_Float16)hv);
    unsigned up   = (unsigned)__shfl_xor((int)hb16, 1, 64);
    if (g==0 && (c&1)==0)
      __hip_atomic_store((unsigned*)(dst + (mt*16 + q*4 + r)*1024 + wg*4 + c),
                         hb16 | (up<<16),
                         __ATOMIC_RELAXED, __HIP_MEMORY_SCOPE_AGENT);
  }
}

__global__ __launch_bounds__(128, 1) void lstm_persist(
    const _Float16* __restrict__ wrec, const _Float16* __restrict__ zx0,
    const float* __restrict__ b1g, _Float16* __restrict__ h0b,
    _Float16* __restrict__ h1a, unsigned int* __restrict__ flags)
{
  extern __shared__ _Float16 lds[];
  _Float16* w0  = lds;            // 16384 halves
  _Float16* w1  = lds + 16384;
  _Float16* w2  = lds + 32768;

  const int wg = blockIdx.x, tid = threadIdx.x;
  const int wv = tid>>6, l = tid&63, q = l>>4, c = l&15;
  const int g = (c>>2);           // gate of own column
  const int mt = wv;              // wave0 rows 0-15, wave1 rows 16-31
  const int row = mt*16 + c;      // A-frag row this lane loads
  const int grp = wg >> 3;        // 32 groups of 8

  unsigned int* gcnt = flags + grp*64;        // 256B apart
  unsigned int* root = flags + 2048;          // own line
  unsigned int* go   = flags + 4096;          // go[g2] at 4096 + g2*64

  { // stage this WG's weight slice: 98304 B = 6144 uint4
    const uint4* src = (const uint4*)(wrec + (size_t)wg*49152);
    uint4* dst = (uint4*)lds;
    for (int i=tid; i<6144; i+=128) dst[i] = src[i];
  }
  float c0[4] = {0,0,0,0}, c1[4] = {0,0,0,0};
  const float b1v = b1g[g*1024 + wg*4 + (c&3)];
  __syncthreads();

  // ---------- prologue: A(0): h0(0) = act(Zx0[0]) (h0(-1)=0) ----------
  {
    const _Float16* zsrc = zx0 + ((size_t)wg*32 + mt*16 + q*4)*16 + c;
    floatx4 a;
    a[0]=(float)zsrc[0]; a[1]=(float)zsrc[16]; a[2]=(float)zsrc[32]; a[3]=(float)zsrc[48];
    gates_store(a, c0, h0b, g, c, mt, q, wg);   // parity 0
  }

  for (int t=0; t<512; ++t){
    // prefetch zx0 for A(t+1) (register-resident across the barrier)
    int tn = (t<511) ? t+1 : 511;
    const _Float16* zsrc = zx0 + ((size_t)(tn*256 + wg)*32 + mt*16 + q*4)*16 + c;
    float pz0=(float)zsrc[0], pz1=(float)zsrc[16], pz2=(float)zsrc[32], pz3=(float)zsrc[48];

    __syncthreads();   // drains vmcnt: h0(t)/h1(t-1) stores visible at LLC
    // ---------- device barrier: 32x8 tree + 32-line go broadcast ----------
    if (tid==0){
      unsigned tgt = (unsigned)(t+1);
      unsigned o = __hip_atomic_fetch_add(gcnt, 1u, __ATOMIC_RELAXED,
                                          __HIP_MEMORY_SCOPE_AGENT);
      if (o == 8u*tgt - 1u){
        unsigned r = __hip_atomic_fetch_add(root, 1u, __ATOMIC_RELAXED,
                                            __HIP_MEMORY_SCOPE_AGENT);
        if (r == 32u*tgt - 1u){
          #pragma unroll
          for (int g2=0; g2<32; ++g2)
            __hip_atomic_store(go + g2*64, tgt, __ATOMIC_RELAXED,
                               __HIP_MEMORY_SCOPE_AGENT);
        }
      }
      while (__hip_atomic_load(go + grp*64, __ATOMIC_RELAXED,
                               __HIP_MEMORY_SCOPE_AGENT) < tgt)
        __builtin_amdgcn_s_sleep(1);
    }
    __syncthreads();
    // NO acquire fence: h1a[t-1] lines are fresh (never cached by any XCD,
    // producers stored uncached to LLC); h0b is read uncached below; zx0 and
    // weights are read-only; __syncthreads orders compiler+HW.

    // ---------- merged compute: B(t) and A(t+1) ----------
    const _Float16* h0c = h0b + (size_t)(t&1)*32768 + row*1024 + q*8;
    floatx4 aA0={0,0,0,0}, aA1={0,0,0,0};
    floatx4 aB0={b1v,b1v,b1v,b1v}, aB1={0,0,0,0};
    floatx4 aC0={0,0,0,0}, aC1={0,0,0,0};
    if (t > 0){
      const _Float16* h1p = h1a + (size_t)(t-1)*32768 + row*1024 + q*8;
      #pragma unroll
      for (int s=0; s<16; ++s){
        aC0 = __builtin_amdgcn_mfma_f32_16x16x32_f16(AF(h1p,s),    BF(w2,s),    aC0,0,0,0);
        aC1 = __builtin_amdgcn_mfma_f32_16x16x32_f16(AF(h1p,16+s), BF(w2,16+s), aC1,0,0,0);
      }
    }
    #pragma unroll
    for (int s=0; s<16; ++s){
      half8 f0 = AFU(h0c,s), f1 = AFU(h0c,16+s);
      aB0 = __builtin_amdgcn_mfma_f32_16x16x32_f16(f0, BF(w1,s),    aB0,0,0,0);
      aB1 = __builtin_amdgcn_mfma_f32_16x16x32_f16(f1, BF(w1,16+s), aB1,0,0,0);
      aA0 = __builtin_amdgcn_mfma_f32_16x16x32_f16(f0, BF(w0,s),    aA0,0,0,0);
      aA1 = __builtin_amdgcn_mfma_f32_16x16x32_f16(f1, BF(w0,16+s), aA1,0,0,0);
    }
    // B(t): h1(t)
    {
      floatx4 z1 = (aB0+aB1)+(aC0+aC1);
      gates_store(z1, c1, h1a + (size_t)t*32768, g, c, mt, q, wg);
    }
    // A(t+1): h0(t+1)
    if (t < 511){
      floatx4 z0 = aA0+aA1;
      z0[0]+=pz0; z0[1]+=pz1; z0[2]+=pz2; z0[3]+=pz3;
      gates_store(z0, c0, h0b + (size_t)((t+1)&1)*32768, g, c, mt, q, wg);
    }
  }
}

// ---------------- Y = H1 @ Wd + bd -----------------------------------------
__global__ __launch_bounds__(256) void wd_gemm(const _Float16* __restrict__ h1a,
                                               const _Float16* __restrict__ wda,
                                               const float* __restrict__ bd,
                                               float* __restrict__ y){
  int mb = blockIdx.x;   // 512 blocks of 32 rows (rows = t*32+b)
  int nb = blockIdx.y;   // 4 blocks of 128 cols
  int tid = threadIdx.x, wv = tid>>6, l = tid&63, q = l>>4, c = l&15;
  int mt = wv & 1, nh = wv >> 1;
  floatx4 acc[4];
  #pragma unroll
  for (int gg=0; gg<4; ++gg) acc[gg] = (floatx4){0.f,0.f,0.f,0.f};
  const _Float16* arow = h1a + (size_t)(mb*32 + mt*16 + c)*1024;
  #pragma unroll 4
  for (int ks=0; ks<32; ++ks){
    int kc = ks*4 + q;
    half8 a = *(const half8*)(arow + kc*8);
    #pragma unroll
    for (int gg=0; gg<4; ++gg){
      int nt = nb*8 + nh*4 + gg;
      half8 b = *(const half8*)(wda + ((size_t)(nt*128 + kc)*16 + c)*8);
      acc[gg] = __builtin_amdgcn_mfma_f32_16x16x32_f16(a,b,acc[gg],0,0,0);
    }
  }
  #pragma unroll
  for (int gg=0; gg<4; ++gg){
    int o = nb*128 + nh*64 + gg*16 + c;
    float bdv = bd[o];
    #pragma unroll
    for (int r=0;r<4;++r){
      int row = mb*32 + mt*16 + q*4 + r;
      int tt = row >> 5, bb = row & 31;
      y[(size_t)bb*262144 + tt*512 + o] = acc[gg][r] + bdv;
    }
  }
}

// ---------------------------------------------------------------------------
extern "C" void kernel_launch(void* const* d_in, const int* in_sizes, int n_in,
                              void* d_out, int out_size, void* d_ws, size_t ws_size,
                              hipStream_t stream){
  const float* x   = (const float*)d_in[0];
  const float* Wx0 = (const float*)d_in[1];
  const float* Wh0 = (const float*)d_in[2];
  const float* b0  = (const float*)d_in[3];
  const float* Wx1 = (const float*)d_in[4];
  const float* Wh1 = (const float*)d_in[5];
  const float* b1  = (const float*)d_in[6];
  const float* Wd  = (const float*)d_in[7];
  const float* bd  = (const float*)d_in[8];
  float* y = (float*)d_out;
  char* ws = (char*)d_ws;

  _Float16* wrec = (_Float16*)(ws + WREC_OFF);
  _Float16* wx0a = (_Float16*)(ws + WX0_OFF);
  _Float16* wda  = (_Float16*)(ws + WD_OFF);
  _Float16* xh   = (_Float16*)(ws + XH_OFF);
  _Float16* zx0  = (_Float16*)(ws + ZX0_OFF);
  _Float16* h0b  = (_Float16*)(ws + H0_OFF);
  _Float16* h1a  = (_Float16*)(ws + H1_OFF);
  unsigned int* flags = (unsigned int*)(ws + FLAGS_OFF);

  hipMemsetAsync(flags, 0, 24576, stream);
  conv_wrec<<<dim3(6144), dim3(256), 0, stream>>>(Wh0, Wx1, Wh1, wrec);
  conv_wx0 <<<dim3(1024), dim3(256), 0, stream>>>(Wx0, wx0a);
  conv_wd  <<<dim3(256),  dim3(256), 0, stream>>>(Wd, wda);
  conv_x   <<<dim3(8192), dim3(256), 0, stream>>>(x, xh);
  zx0_gemm <<<dim3(512,64), dim3(64), 0, stream>>>(xh, wx0a, b0, zx0);
  hipFuncSetAttribute((const void*)lstm_persist,
                      hipFuncAttributeMaxDynamicSharedMemorySize, 98304);
  lstm_persist<<<dim3(256), dim3(128), 98304, stream>>>(wrec, zx0, b1, h0b, h1a, flags);
  wd_gemm  <<<dim3(512,4), dim3(256), 0, stream>>>(h1a, wda, bd, y);
}